// Round 1
// baseline (114.569 us; speedup 1.0000x reference)
//
#include <hip/hip_runtime.h>
#include <cstdint>
#include <cstddef>

#define B 4096
#define S 200
#define V 33
#define T 50
#define EPSV 1e-08

// ws layout (bytes):
// [0]  double ll_sum
// [8]  double nll_sum
// [16] unsigned long long count   (= sum_b (len_b - 1))
// [24] int event_mode  (0 = int32, 1 = uint8/bool, 2 = int64)
// [28] pad
// [32] int lengths[B]

__device__ __forceinline__ bool is_nan_bits(float x) {
    uint32_t u = __float_as_uint(x);
    return (u & 0x7F800000u) == 0x7F800000u && (u & 0x007FFFFFu) != 0u;
}

// ---- detect how the bool 'event' array is stored ---------------------------
__global__ void detect_event_mode(const uint32_t* __restrict__ ev_words, int* mode) {
    __shared__ int s_gt1, s_oddnz;
    if (threadIdx.x == 0) { s_gt1 = 0; s_oddnz = 0; }
    __syncthreads();
    int gt1 = 0, oddnz = 0;
    // scan exactly B bytes = B/4 u32 words: safe under every interpretation
    for (int i = threadIdx.x; i < B / 4; i += blockDim.x) {
        uint32_t w = ev_words[i];
        if (w > 1u) gt1 = 1;
        if ((i & 1) && w != 0u) oddnz = 1;
    }
    if (gt1)   atomicOr(&s_gt1, 1);
    if (oddnz) atomicOr(&s_oddnz, 1);
    __syncthreads();
    if (threadIdx.x == 0) {
        // bytes packed -> some word > 1 (w.h.p.); int64 -> all odd (high) words zero
        *mode = s_gt1 ? 1 : (s_oddnz ? 0 : 2);
    }
}

// ---- lengths via binary search on the NaN suffix ---------------------------
__global__ void compute_lengths(const float* __restrict__ data,
                                int* __restrict__ lengths,
                                unsigned long long* count) {
    int b = blockIdx.x * blockDim.x + threadIdx.x;
    if (b >= B) return;
    int lo = 0, hi = S;
    while (lo < hi) {
        int mid = (lo + hi) >> 1;
        float v = data[((size_t)b * S + mid) * V + 1];
        if (is_nan_bits(v)) hi = mid; else lo = mid + 1;
    }
    lengths[b] = lo;                       // first NaN row == valid length
    atomicAdd(count, (unsigned long long)(lo - 1));
}

// ---- main longitudinal loss kernel ------------------------------------------
// Each half-wave (32 lanes) handles one row s: lane v loads data[b,s,1+v] and
// long_pred[b,s-1,v]. 8 rows per 256-thread block iteration; grid-stride over
// (b, chunk) pairs.
constexpr int ROWS_PER_CHUNK = 8;
constexpr int CHUNKS_PER_B   = (S - 1 + ROWS_PER_CHUNK - 1) / ROWS_PER_CHUNK; // 25

template <bool USE_LEN>
__global__ __launch_bounds__(256)
void long_loss_kernel(const float* __restrict__ long_pred,
                      const float* __restrict__ data,
                      const int* __restrict__ lengths,
                      double* ll_sum, unsigned long long* count) {
    const int tid = threadIdx.x;
    const int r   = tid >> 5;    // row within chunk [0,8)
    const int v   = tid & 31;    // feature column [0,32)
    float acc = 0.0f;
    int   cnt = 0;

    const int total_chunks = B * CHUNKS_PER_B;
    for (int q = blockIdx.x; q < total_chunks; q += gridDim.x) {
        int b  = q / CHUNKS_PER_B;
        int c  = q - b * CHUNKS_PER_B;
        int s0 = 1 + c * ROWS_PER_CHUNK;
        int s  = s0 + r;
        if (USE_LEN) {
            int len = lengths[b];
            if (s0 >= len) continue;       // uniform across block
            if (s < len) {
                float d  = data[((size_t)b * S + s) * V + 1 + v];
                float lp = long_pred[((size_t)b * S + (s - 1)) * (V - 1) + v];
                float df = lp - d;
                acc = fmaf(df, df, acc);
            }
        } else {
            if (s < S) {
                float d = data[((size_t)b * S + s) * V + 1 + v];
                if (!is_nan_bits(d)) {
                    float lp = long_pred[((size_t)b * S + (s - 1)) * (V - 1) + v];
                    float df = lp - d;
                    acc = fmaf(df, df, acc);
                    if (v == 0) cnt++;
                }
            }
        }
    }

    // block reduction: 64-lane shuffle, then 4 wave partials via LDS
    for (int off = 32; off > 0; off >>= 1) acc += __shfl_down(acc, off);
    if (!USE_LEN)
        for (int off = 32; off > 0; off >>= 1) cnt += __shfl_down(cnt, off);

    __shared__ float s_sum[4];
    __shared__ int   s_cnt[4];
    int wid  = tid >> 6;
    int lane = tid & 63;
    if (lane == 0) { s_sum[wid] = acc; s_cnt[wid] = cnt; }
    __syncthreads();
    if (tid == 0) {
        double bs = 0.0; int bc = 0;
        for (int i = 0; i < 4; ++i) { bs += (double)s_sum[i]; bc += s_cnt[i]; }
        if (bs != 0.0) atomicAdd(ll_sum, bs);
        if (!USE_LEN && bc) atomicAdd(count, (unsigned long long)bc);
    }
}

// ---- survival NLL: one wave per batch row -----------------------------------
__global__ __launch_bounds__(256)
void nll_kernel(const float* __restrict__ surv_pred,
                const void*  __restrict__ event,
                const float* __restrict__ event_time,
                const float* __restrict__ time_range,
                const int*   __restrict__ mode_p,
                double* nll_sum) {
    int wib  = threadIdx.x >> 6;
    int lane = threadIdx.x & 63;
    int b    = blockIdx.x * (blockDim.x >> 6) + wib;
    if (b >= B) return;

    int mode = *mode_p;
    float sv = (lane < T) ? surv_pred[b * T + lane] : 0.0f;
    float tr = (lane < T) ? time_range[lane] : 0.0f;
    float et = event_time[b];

    // searchsorted(time_range, et, 'right') - 1  ==  popcount(tr[t] <= et) - 1
    unsigned long long bal = __ballot(lane < T && tr <= et);
    int idx = (int)__popcll(bal) - 1;

    // tail = sum_{t >= idx+1, t < T} surv  (reverse cumsum at idx+1)
    float tval = (lane < T && lane >= idx + 1) ? sv : 0.0f;
    for (int off = 32; off > 0; off >>= 1) tval += __shfl_down(tval, off);

    int idx_c = idx < 0 ? 0 : idx;           // jax take_along_axis clips
    float at_idx = __shfl(sv, idx_c);

    bool ev;
    if (mode == 1)      ev = ((const unsigned char*)event)[b] != 0;
    else if (mode == 2) ev = ((const int*)event)[2 * b] != 0;   // LE low word
    else                ev = ((const int*)event)[b] != 0;

    if (lane == 0) {
        float f = ev ? at_idx : ((idx + 1 < T) ? tval : 0.0f);
        if (f == 0.0f) f = (float)EPSV;
        atomicAdd(nll_sum, -log((double)f));
    }
}

// ---- finalize ----------------------------------------------------------------
__global__ void finalize_kernel(const double* ll_sum, const double* nll_sum,
                                const unsigned long long* count, float* out) {
    double denom = (double)(*count) * (double)(V - 1);
    double ll  = *ll_sum / denom;
    double nll = *nll_sum / (double)B;
    out[0] = (float)(nll + ll);
}

extern "C" void kernel_launch(void* const* d_in, const int* in_sizes, int n_in,
                              void* d_out, int out_size, void* d_ws, size_t ws_size,
                              hipStream_t stream) {
    const float* long_pred  = (const float*)d_in[0];
    const float* surv_pred  = (const float*)d_in[1];
    const float* data       = (const float*)d_in[2];
    const void*  event      = d_in[3];
    const float* event_time = (const float*)d_in[4];
    const float* time_range = (const float*)d_in[5];
    float* out = (float*)d_out;

    double* ll_sum  = (double*)d_ws;
    double* nll_sum = (double*)((char*)d_ws + 8);
    unsigned long long* count = (unsigned long long*)((char*)d_ws + 16);
    int* mode    = (int*)((char*)d_ws + 24);
    int* lengths = (int*)((char*)d_ws + 32);

    hipMemsetAsync(d_ws, 0, 32, stream);
    detect_event_mode<<<1, 256, 0, stream>>>((const uint32_t*)event, mode);

    bool use_len = ws_size >= (size_t)(32 + B * (int)sizeof(int));
    if (use_len) {
        compute_lengths<<<(B + 63) / 64, 64, 0, stream>>>(data, lengths, count);
        long_loss_kernel<true><<<2048, 256, 0, stream>>>(long_pred, data, lengths, ll_sum, count);
    } else {
        long_loss_kernel<false><<<2048, 256, 0, stream>>>(long_pred, data, nullptr, ll_sum, count);
    }
    nll_kernel<<<B / 4, 256, 0, stream>>>(surv_pred, event, event_time, time_range, mode, nll_sum);
    finalize_kernel<<<1, 1, 0, stream>>>(ll_sum, nll_sum, count, out);
}

// Round 2
// 58.557 us; speedup vs baseline: 1.9566x; 1.9566x over previous
//
#include <hip/hip_runtime.h>
#include <cstdint>
#include <cstddef>

#define B 4096
#define S 200
#define V 33
#define T 50
#define EPSV 1e-08
#define NLL_BLOCKS 64
#define ROWS_PER_NLL_BLOCK (B / NLL_BLOCKS)   // 64

// ws layout:
// [0]                double ll_part[B]         32 KiB
// [32768]            unsigned cnt_part[B]      16 KiB
// [49152]            double nll_part[64]       512 B
// Every slot is unconditionally written by its owning block each call,
// so no zero-init / memset node is required (poison-safe, replay-safe).

__device__ __forceinline__ bool is_nan_bits(float x) {
    uint32_t u = __float_as_uint(x);
    return (u & 0x7F800000u) == 0x7F800000u && (u & 0x007FFFFFu) != 0u;
}

__global__ __launch_bounds__(256)
void fused_kernel(const float* __restrict__ long_pred,
                  const float* __restrict__ surv_pred,
                  const float* __restrict__ data,
                  const uint32_t* __restrict__ event_words,
                  const float* __restrict__ event_time,
                  const float* __restrict__ time_range,
                  double* __restrict__ ll_part,
                  unsigned int* __restrict__ cnt_part,
                  double* __restrict__ nll_part) {
    const int tid = threadIdx.x;
    const int blk = blockIdx.x;

    if (blk < B) {
        // ---------------- longitudinal loss: one block per b ----------------
        const int b = blk;
        const float* __restrict__ dbase  = data      + (size_t)b * (S * V);        // 6600 floats
        const float* __restrict__ lpbase = long_pred + (size_t)b * (S * (V - 1));  // 6400 floats
        constexpr int NELEM = S * V;  // 6600

        float    acc = 0.0f;
        unsigned cnt = 0;

        // stream rows 1..S-1 flat; rows are fully-NaN past len, so any
        // element's NaN bit identifies an invalid row. Early-exit when an
        // entire 256-dword chunk is dead (NaN suffix reached).
        for (int start = V; start < NELEM; start += 256) {
            int  idx  = start + tid;
            int  dead = 1;
            if (idx < NELEM) {
                float d = dbase[idx];
                if (!is_nan_bits(d)) {
                    dead = 0;
                    int s   = idx / 33;           // >= 1 here
                    int col = idx - s * 33;       // 0..32
                    if (col != 0) {
                        // lp index = (s-1)*32 + (col-1) = idx - s - 33
                        float lp = lpbase[idx - s - 33];
                        float df = lp - d;
                        acc = fmaf(df, df, acc);
                        if (col == 1) cnt++;      // one count per valid row
                    }
                }
            }
            if (__syncthreads_and(dead)) break;
        }

        // block reduction: 64-lane shuffle then cross-wave via LDS
        for (int off = 32; off > 0; off >>= 1) {
            acc += __shfl_down(acc, off);
            cnt += __shfl_down(cnt, off);
        }
        __shared__ float    s_sum[4];
        __shared__ unsigned s_cnt[4];
        int wib  = tid >> 6;
        int lane = tid & 63;
        if (lane == 0) { s_sum[wib] = acc; s_cnt[wib] = cnt; }
        __syncthreads();
        if (tid == 0) {
            double   bs = 0.0;
            unsigned bc = 0;
            for (int i = 0; i < 4; ++i) { bs += (double)s_sum[i]; bc += s_cnt[i]; }
            ll_part[b]  = bs;
            cnt_part[b] = bc;
        }
    } else {
        // ---------------- survival NLL: 64 rows per block --------------------
        const int nb = blk - B;

        // detect event storage (redundant per block; 4 KiB, L2-resident)
        __shared__ int s_gt1, s_oddnz;
        if (tid == 0) { s_gt1 = 0; s_oddnz = 0; }
        __syncthreads();
        int gt1 = 0, oddnz = 0;
        for (int i = tid; i < B / 4; i += 256) {     // exactly B bytes: always safe
            uint32_t w = event_words[i];
            if (w > 1u) gt1 = 1;
            if ((i & 1) && w != 0u) oddnz = 1;
        }
        if (gt1)   atomicOr(&s_gt1, 1);
        if (oddnz) atomicOr(&s_oddnz, 1);
        __syncthreads();
        const int mode = s_gt1 ? 1 : (s_oddnz ? 0 : 2);  // 1=u8, 0=i32, 2=i64

        const int wib  = tid >> 6;
        const int lane = tid & 63;
        double nsum = 0.0;

        for (int r = 0; r < ROWS_PER_NLL_BLOCK / 4; ++r) {
            int b = nb * ROWS_PER_NLL_BLOCK + r * 4 + wib;
            float sv = (lane < T) ? surv_pred[b * T + lane] : 0.0f;
            float tr = (lane < T) ? time_range[lane] : 0.0f;
            float et = event_time[b];

            // searchsorted(time_range, et, 'right') - 1
            unsigned long long bal = __ballot(lane < T && tr <= et);
            int idx = (int)__popcll(bal) - 1;

            // tail = sum_{t >= idx+1} surv_pred[b,t]
            float tval = (lane < T && lane >= idx + 1) ? sv : 0.0f;
            for (int off = 32; off > 0; off >>= 1) tval += __shfl_down(tval, off);

            int   idx_c   = idx < 0 ? 0 : idx;
            float at_idx  = __shfl(sv, idx_c);

            bool ev;
            if (mode == 1)      ev = ((const unsigned char*)event_words)[b] != 0;
            else if (mode == 2) ev = ((const int*)event_words)[2 * b] != 0;  // LE low word
            else                ev = ((const int*)event_words)[b] != 0;

            if (lane == 0) {
                float f = ev ? at_idx : ((idx + 1 < T) ? tval : 0.0f);
                if (f == 0.0f) f = (float)EPSV;
                nsum += -log((double)f);
            }
        }

        __shared__ double s_n[4];
        if (lane == 0) s_n[wib] = nsum;
        __syncthreads();
        if (tid == 0) nll_part[nb] = s_n[0] + s_n[1] + s_n[2] + s_n[3];
    }
}

__global__ __launch_bounds__(256)
void finalize_kernel(const double* __restrict__ ll_part,
                     const unsigned* __restrict__ cnt_part,
                     const double* __restrict__ nll_part,
                     float* __restrict__ out) {
    const int tid = threadIdx.x;
    double             ls = 0.0;
    unsigned long long cs = 0;
    double             ns = 0.0;
    for (int i = tid; i < B; i += 256) { ls += ll_part[i]; cs += cnt_part[i]; }
    if (tid < NLL_BLOCKS) ns = nll_part[tid];

    for (int off = 32; off > 0; off >>= 1) {
        ls += __shfl_down(ls, off);
        cs += __shfl_down(cs, off);
        ns += __shfl_down(ns, off);
    }
    __shared__ double             sl[4], sn[4];
    __shared__ unsigned long long sc[4];
    int wib = tid >> 6, lane = tid & 63;
    if (lane == 0) { sl[wib] = ls; sc[wib] = cs; sn[wib] = ns; }
    __syncthreads();
    if (tid == 0) {
        double L = 0.0, N = 0.0;
        unsigned long long C = 0;
        for (int i = 0; i < 4; ++i) { L += sl[i]; C += sc[i]; N += sn[i]; }
        double denom = (double)C * (double)(V - 1);
        out[0] = (float)(N / (double)B + L / denom);
    }
}

extern "C" void kernel_launch(void* const* d_in, const int* in_sizes, int n_in,
                              void* d_out, int out_size, void* d_ws, size_t ws_size,
                              hipStream_t stream) {
    const float* long_pred  = (const float*)d_in[0];
    const float* surv_pred  = (const float*)d_in[1];
    const float* data       = (const float*)d_in[2];
    const void*  event      = d_in[3];
    const float* event_time = (const float*)d_in[4];
    const float* time_range = (const float*)d_in[5];
    float* out = (float*)d_out;

    double*   ll_part  = (double*)d_ws;
    unsigned* cnt_part = (unsigned*)((char*)d_ws + 32768);
    double*   nll_part = (double*)((char*)d_ws + 49152);

    fused_kernel<<<B + NLL_BLOCKS, 256, 0, stream>>>(
        long_pred, surv_pred, data, (const uint32_t*)event, event_time,
        time_range, ll_part, cnt_part, nll_part);
    finalize_kernel<<<1, 256, 0, stream>>>(ll_part, cnt_part, nll_part, out);
}

// Round 3
// 53.433 us; speedup vs baseline: 2.1442x; 1.0959x over previous
//
#include <hip/hip_runtime.h>
#include <cstdint>
#include <cstddef>

#define B 4096
#define S 200
#define V 33
#define T 50
#define EPSV 1e-08
#define NLL_BLOCKS 64
#define ROWS_PER_NLL_BLOCK (B / NLL_BLOCKS)   // 64

// ws layout:
// [0]      double ll_part[B]       32 KiB
// [32768]  unsigned cnt_part[B]    16 KiB
// [49152]  double nll_part[64]     512 B
// Every slot is unconditionally written by its owning block each call:
// no memset node needed, poison/replay-safe.

__device__ __forceinline__ bool is_nan_bits(float x) {
    uint32_t u = __float_as_uint(x);
    return (u & 0x7F800000u) == 0x7F800000u && (u & 0x007FFFFFu) != 0u;
}

__global__ __launch_bounds__(256)
void fused_kernel(const float* __restrict__ long_pred,
                  const float* __restrict__ surv_pred,
                  const float* __restrict__ data,
                  const uint32_t* __restrict__ event_words,
                  const float* __restrict__ event_time,
                  const float* __restrict__ time_range,
                  double* __restrict__ ll_part,
                  unsigned int* __restrict__ cnt_part,
                  double* __restrict__ nll_part) {
    const int tid = threadIdx.x;
    const int blk = blockIdx.x;

    if (blk < B) {
        // ------------- longitudinal loss: one block per batch row -----------
        const int b = blk;
        const float* __restrict__ dbase  = data      + (size_t)b * (S * V);
        const float* __restrict__ lpbase = long_pred + (size_t)b * (S * (V - 1));

        // 1 parallel probe round: validity is a prefix, so count == length
        int valid = 0;
        if (tid < S) valid = !is_nan_bits(dbase[(size_t)tid * V + 1]);
        const int len = __syncthreads_count(valid);

        // stream rows 1..len-1; half-wave per row, lane = feature column.
        // No barriers, no NaN checks -> loads pipeline freely across iters.
        const int r = tid >> 5;        // row offset 0..7
        const int c = tid & 31;        // feature col 0..31
        float acc = 0.0f;
        #pragma unroll 2
        for (int s = 1 + r; s < len; s += 8) {
            float d  = dbase[s * V + 1 + c];
            float lp = lpbase[(s - 1) * (V - 1) + c];
            float df = lp - d;
            acc = fmaf(df, df, acc);
        }

        for (int off = 32; off > 0; off >>= 1) acc += __shfl_down(acc, off);
        __shared__ float s_sum[4];
        int wib  = tid >> 6;
        int lane = tid & 63;
        if (lane == 0) s_sum[wib] = acc;
        __syncthreads();
        if (tid == 0) {
            double bs = (double)s_sum[0] + (double)s_sum[1]
                      + (double)s_sum[2] + (double)s_sum[3];
            ll_part[b]  = bs;
            cnt_part[b] = (unsigned)(len - 1);
        }
    } else {
        // ------------- survival NLL: 64 batch rows per block -----------------
        const int nb = blk - B;

        // detect event storage layout (redundant per block; 4 KiB, L2-hit)
        __shared__ int s_gt1, s_oddnz;
        if (tid == 0) { s_gt1 = 0; s_oddnz = 0; }
        __syncthreads();
        int gt1 = 0, oddnz = 0;
        for (int i = tid; i < B / 4; i += 256) {   // exactly B bytes: safe
            uint32_t w = event_words[i];
            if (w > 1u) gt1 = 1;
            if ((i & 1) && w != 0u) oddnz = 1;
        }
        if (gt1)   atomicOr(&s_gt1, 1);
        if (oddnz) atomicOr(&s_oddnz, 1);
        __syncthreads();
        const int mode = s_gt1 ? 1 : (s_oddnz ? 0 : 2);  // 1=u8, 0=i32, 2=i64

        const int wib  = tid >> 6;
        const int lane = tid & 63;
        double nsum = 0.0;

        for (int r = 0; r < ROWS_PER_NLL_BLOCK / 4; ++r) {
            int b = nb * ROWS_PER_NLL_BLOCK + r * 4 + wib;
            float sv = (lane < T) ? surv_pred[b * T + lane] : 0.0f;
            float tr = (lane < T) ? time_range[lane] : 0.0f;
            float et = event_time[b];

            // searchsorted(time_range, et, 'right') - 1
            unsigned long long bal = __ballot(lane < T && tr <= et);
            int idx = (int)__popcll(bal) - 1;

            // tail = sum_{t >= idx+1} surv_pred[b,t]
            float tval = (lane < T && lane >= idx + 1) ? sv : 0.0f;
            for (int off = 32; off > 0; off >>= 1) tval += __shfl_down(tval, off);

            int   idx_c  = idx < 0 ? 0 : idx;
            float at_idx = __shfl(sv, idx_c);

            bool ev;
            if (mode == 1)      ev = ((const unsigned char*)event_words)[b] != 0;
            else if (mode == 2) ev = ((const int*)event_words)[2 * b] != 0;
            else                ev = ((const int*)event_words)[b] != 0;

            if (lane == 0) {
                float f = ev ? at_idx : ((idx + 1 < T) ? tval : 0.0f);
                if (f == 0.0f) f = (float)EPSV;
                nsum += -log((double)f);
            }
        }

        __shared__ double s_n[4];
        if (lane == 0) s_n[wib] = nsum;
        __syncthreads();
        if (tid == 0) nll_part[nb] = s_n[0] + s_n[1] + s_n[2] + s_n[3];
    }
}

__global__ __launch_bounds__(256)
void finalize_kernel(const double* __restrict__ ll_part,
                     const unsigned* __restrict__ cnt_part,
                     const double* __restrict__ nll_part,
                     float* __restrict__ out) {
    const int tid = threadIdx.x;
    double             ls = 0.0;
    unsigned long long cs = 0;
    double             ns = 0.0;
    for (int i = tid; i < B; i += 256) { ls += ll_part[i]; cs += cnt_part[i]; }
    if (tid < NLL_BLOCKS) ns = nll_part[tid];

    for (int off = 32; off > 0; off >>= 1) {
        ls += __shfl_down(ls, off);
        cs += __shfl_down(cs, off);
        ns += __shfl_down(ns, off);
    }
    __shared__ double             sl[4], sn[4];
    __shared__ unsigned long long sc[4];
    int wib = tid >> 6, lane = tid & 63;
    if (lane == 0) { sl[wib] = ls; sc[wib] = cs; sn[wib] = ns; }
    __syncthreads();
    if (tid == 0) {
        double L = 0.0, N = 0.0;
        unsigned long long C = 0;
        for (int i = 0; i < 4; ++i) { L += sl[i]; C += sc[i]; N += sn[i]; }
        double denom = (double)C * (double)(V - 1);
        out[0] = (float)(N / (double)B + L / denom);
    }
}

extern "C" void kernel_launch(void* const* d_in, const int* in_sizes, int n_in,
                              void* d_out, int out_size, void* d_ws, size_t ws_size,
                              hipStream_t stream) {
    const float* long_pred  = (const float*)d_in[0];
    const float* surv_pred  = (const float*)d_in[1];
    const float* data       = (const float*)d_in[2];
    const void*  event      = d_in[3];
    const float* event_time = (const float*)d_in[4];
    const float* time_range = (const float*)d_in[5];
    float* out = (float*)d_out;

    double*   ll_part  = (double*)d_ws;
    unsigned* cnt_part = (unsigned*)((char*)d_ws + 32768);
    double*   nll_part = (double*)((char*)d_ws + 49152);

    fused_kernel<<<B + NLL_BLOCKS, 256, 0, stream>>>(
        long_pred, surv_pred, data, (const uint32_t*)event, event_time,
        time_range, ll_part, cnt_part, nll_part);
    finalize_kernel<<<1, 256, 0, stream>>>(ll_part, cnt_part, nll_part, out);
}